// Round 3
// baseline (26.622 us; speedup 1.0000x reference)
//
#include <hip/hip_runtime.h>

// SphericalHarmonicsLighting — B=16, V=262144 (2^18)
// E[b,v,c] = sum_j Nown[j] * (M[c][row i] . Naug[b, (4v mod V)+j]),
//   i = v>>16 (block-uniform), Nown/Naug = (nx,ny,nz,1)  [torch .view() quirk]
//
// R3 structure: 256-thread block = 256 vertices; NO __syncthreads.
// Each wave stages its own 3KiB neighbor chunk (global_load_lds x3, fully
// coalesced), issues its own-normal loads, then one s_waitcnt vmcnt(0).
// 12KiB LDS/block -> 8 blocks/CU -> 32 waves/CU (100% occupancy).
// LDS reads: ds_read_b128 at 48B lane stride -> all 32 banks, 8 lanes/bank
// (b128 minimum) = conflict-free.

#define SH_V 262144
#define SH_B 16

__global__ __launch_bounds__(256, 8) void sh_lighting_kernel(
    const float* __restrict__ normals,   // [B, V, 3]
    const float* __restrict__ sh,        // [27]
    float* __restrict__ out)             // [B, V, 3]
{
    __shared__ float nbr[256 * 12];      // 12 KiB

    const int tid  = threadIdx.x;
    const int lane = tid & 63;
    const int w    = tid >> 6;           // wave id 0..3
    const int blk  = blockIdx.x;
    const int b    = blk >> 10;          // 1024 blocks per batch image
    const int rem  = blk & 1023;
    const int v0   = rem << 8;           // first vertex of this block (batch-local)
    const int i    = rem >> 8;           // M row index 0..3 (block-uniform)
    const int nb0  = (rem & 255) << 10;  // neighbor window base = (4*v0) mod V

    const float* nbase = normals + (size_t)b * (SH_V * 3);

    // ---- per-wave coalesced staging: 3KiB chunk for this wave's 64 vertices ----
    {
        const float* src = nbase + (size_t)nb0 * 3;  // block window, 12KiB
#pragma unroll
        for (int k = 0; k < 3; ++k) {
            const int idx = 192 * w + 64 * k + lane;    // float4 index within window
            __builtin_amdgcn_global_load_lds(
                (const __attribute__((address_space(1))) void*)(src + (size_t)idx * 4),
                (__attribute__((address_space(3))) void*)(&nbr[idx * 4]),
                16, 0, 0);
        }
    }

    // ---- own normal load (in flight alongside staging) ----
    const float3 own = *(const float3*)(nbase + (size_t)(v0 + tid) * 3);

    // ---- M row i for each RGB channel (block-uniform i -> scalar branch) ----
    const float c0 = 0.429043f, c1 = 0.511664f, c2 = 0.743125f,
                c3 = 0.886227f, c4 = 0.247708f;
    float Mr[3][4];
#pragma unroll
    for (int c = 0; c < 3; ++c) {
        const float L0 = sh[9*c+0], L1 = sh[9*c+1], L2 = sh[9*c+2];
        const float L3 = sh[9*c+3], L4 = sh[9*c+4], L5 = sh[9*c+5];
        const float L6 = sh[9*c+6], L7 = sh[9*c+7], L8 = sh[9*c+8];
        if (i == 0) {
            Mr[c][0] = c0*L8;  Mr[c][1] = c0*L4;  Mr[c][2] = c0*L7;  Mr[c][3] = c1*L3;
        } else if (i == 1) {
            Mr[c][0] = c0*L4;  Mr[c][1] = -c0*L8; Mr[c][2] = c0*L5;  Mr[c][3] = c1*L1;
        } else if (i == 2) {
            Mr[c][0] = c0*L7;  Mr[c][1] = c0*L5;  Mr[c][2] = c2*L6;  Mr[c][3] = c1*L2;
        } else {
            Mr[c][0] = c1*L3;  Mr[c][1] = c1*L1;  Mr[c][2] = c1*L2;  Mr[c][3] = c3*L0 - c4*L6;
        }
    }

    // ---- wait for this wave's staging (and own load); no barrier needed ----
    asm volatile("s_waitcnt vmcnt(0)" ::: "memory");
    __builtin_amdgcn_sched_barrier(0);

    // ---- neighbors from LDS: 3x ds_read_b128, 48B lane stride, conflict-free ----
    const float4* lp = (const float4*)(&nbr[12 * tid]);
    const float4 q0 = lp[0], q1 = lp[1], q2 = lp[2];
    const float ng[12] = {q0.x,q0.y,q0.z,q0.w, q1.x,q1.y,q1.z,q1.w, q2.x,q2.y,q2.z,q2.w};

    // factored: e_c = Mr[c] . (dx,dy,dz,dw)
    const float dx = fmaf(own.x, ng[0], fmaf(own.y, ng[3], fmaf(own.z, ng[6], ng[9])));
    const float dy = fmaf(own.x, ng[1], fmaf(own.y, ng[4], fmaf(own.z, ng[7], ng[10])));
    const float dz = fmaf(own.x, ng[2], fmaf(own.y, ng[5], fmaf(own.z, ng[8], ng[11])));
    const float dw = own.x + own.y + own.z + 1.0f;

    float3 ev;
    ev.x = fmaf(Mr[0][0], dx, fmaf(Mr[0][1], dy, fmaf(Mr[0][2], dz, Mr[0][3] * dw)));
    ev.y = fmaf(Mr[1][0], dx, fmaf(Mr[1][1], dy, fmaf(Mr[1][2], dz, Mr[1][3] * dw)));
    ev.z = fmaf(Mr[2][0], dx, fmaf(Mr[2][1], dy, fmaf(Mr[2][2], dz, Mr[2][3] * dw)));

    // dense store: 12B at 12B lane stride -> contiguous 768B per wave
    *(float3*)(out + (size_t)b * (SH_V * 3) + (size_t)(v0 + tid) * 3) = ev;
}

extern "C" void kernel_launch(void* const* d_in, const int* in_sizes, int n_in,
                              void* d_out, int out_size, void* d_ws, size_t ws_size,
                              hipStream_t stream) {
    // d_in[0] = light (3) -- unused by the reference computation
    const float* normals = (const float*)d_in[1];   // B*V*3
    const float* sh      = (const float*)d_in[2];   // 27
    float* out           = (float*)d_out;           // B*V*3

    const int grid = SH_B * (SH_V / 256);           // 16384 blocks
    sh_lighting_kernel<<<grid, 256, 0, stream>>>(normals, sh, out);
}

// Round 4
// 26.326 us; speedup vs baseline: 1.0113x; 1.0113x over previous
//
#include <hip/hip_runtime.h>

// SphericalHarmonicsLighting — B=16, V=262144 (2^18), QTR = V/4 = 65536
// E[b,v,c] = sum_j Nown[j] * (M[c][row i] . Naug[b, (4v mod V)+j]),
//   i = v>>16 (= quarter index), Naug = (nx,ny,nz,1)  [torch .view() quirk]
//
// R4 key fact: v = u + m*QTR (m=0..3) all share neighbor base 4u (4*QTR = V ≡ 0).
// One block handles u-range [u0,u0+256) for ALL 4 quarters:
//   - neighbor window [4u0, 4u0+1024) staged ONCE (12KB LDS) instead of 4x
//   - wave-local staging (wave w stages exactly the slice its threads read) -> no barrier
//   - thread t: 4 own normals (one per quarter), 4 outputs, using M rows 0..3
// Stores are nontemporal (output never re-read; avoid L2/L3 write-allocate).

#define SH_V 262144
#define SH_B 16
#define QTR  65536

__global__ __launch_bounds__(256, 8) void sh_lighting_kernel(
    const float* __restrict__ normals,   // [B, V, 3]
    const float* __restrict__ sh,        // [27]
    float* __restrict__ out)             // [B, V, 3]
{
    __shared__ float nbr[3072];          // 12 KiB: 1024-vertex neighbor window

    const int tid  = threadIdx.x;
    const int lane = tid & 63;
    const int w    = tid >> 6;           // wave 0..3
    const int blk  = blockIdx.x;
    const int b    = blk >> 8;           // 256 u-blocks per batch image
    const int ublk = blk & 255;
    const int u0   = ublk << 8;          // u in [u0, u0+256), u0+255 < QTR
    const int nb0  = u0 << 2;            // neighbor window base = 4*u0 (< V)

    const float* nbase = normals + (size_t)b * (SH_V * 3);

    // ---- wave-local coalesced staging: wave w stages window float4s [192w, 192w+192) ----
    {
        const float* src = nbase + (size_t)nb0 * 3;   // 12 KiB window
#pragma unroll
        for (int k = 0; k < 3; ++k) {
            const int idx = 192 * w + 64 * k + lane;  // float4 index within window
            __builtin_amdgcn_global_load_lds(
                (const __attribute__((address_space(1))) void*)(src + (size_t)idx * 4),
                (__attribute__((address_space(3))) void*)(&nbr[idx * 4]),
                16, 0, 0);
        }
    }

    // ---- own normals for all 4 quarters (in flight alongside staging) ----
    float3 own[4];
#pragma unroll
    for (int m = 0; m < 4; ++m) {
        own[m] = *(const float3*)(nbase + (size_t)(u0 + tid + m * QTR) * 3);
    }

    // ---- full M[3][4][4] rows (uniform scalar math; no branch needed now) ----
    const float c0 = 0.429043f, c1 = 0.511664f, c2 = 0.743125f,
                c3 = 0.886227f, c4 = 0.247708f;
    float M[3][4][4];
#pragma unroll
    for (int c = 0; c < 3; ++c) {
        const float L0 = sh[9*c+0], L1 = sh[9*c+1], L2 = sh[9*c+2];
        const float L3 = sh[9*c+3], L4 = sh[9*c+4], L5 = sh[9*c+5];
        const float L6 = sh[9*c+6], L7 = sh[9*c+7], L8 = sh[9*c+8];
        M[c][0][0] = c0*L8;  M[c][0][1] = c0*L4;  M[c][0][2] = c0*L7;  M[c][0][3] = c1*L3;
        M[c][1][0] = c0*L4;  M[c][1][1] = -c0*L8; M[c][1][2] = c0*L5;  M[c][1][3] = c1*L1;
        M[c][2][0] = c0*L7;  M[c][2][1] = c0*L5;  M[c][2][2] = c2*L6;  M[c][2][3] = c1*L2;
        M[c][3][0] = c1*L3;  M[c][3][1] = c1*L1;  M[c][3][2] = c1*L2;  M[c][3][3] = c3*L0 - c4*L6;
    }

    // ---- wait for this wave's staging + own loads (no barrier: wave-local) ----
    asm volatile("s_waitcnt vmcnt(0)" ::: "memory");
    __builtin_amdgcn_sched_barrier(0);

    // ---- neighbors: 3x ds_read_b128 at 48B lane stride (conflict-free) ----
    const float4* lp = (const float4*)(&nbr[12 * tid]);
    const float4 q0 = lp[0], q1 = lp[1], q2 = lp[2];
    const float ng[12] = {q0.x,q0.y,q0.z,q0.w, q1.x,q1.y,q1.z,q1.w, q2.x,q2.y,q2.z,q2.w};

    float* obase = out + (size_t)b * (SH_V * 3);

    // ---- 4 outputs per thread: quarter m uses M row m and own[m] ----
#pragma unroll
    for (int m = 0; m < 4; ++m) {
        const float nx = own[m].x, ny = own[m].y, nz = own[m].z;
        const float dx = fmaf(nx, ng[0], fmaf(ny, ng[3], fmaf(nz, ng[6], ng[9])));
        const float dy = fmaf(nx, ng[1], fmaf(ny, ng[4], fmaf(nz, ng[7], ng[10])));
        const float dz = fmaf(nx, ng[2], fmaf(ny, ng[5], fmaf(nz, ng[8], ng[11])));
        const float dw = nx + ny + nz + 1.0f;

        float* op = obase + (size_t)(u0 + tid + m * QTR) * 3;
        __builtin_nontemporal_store(
            fmaf(M[0][m][0], dx, fmaf(M[0][m][1], dy, fmaf(M[0][m][2], dz, M[0][m][3] * dw))), op);
        __builtin_nontemporal_store(
            fmaf(M[1][m][0], dx, fmaf(M[1][m][1], dy, fmaf(M[1][m][2], dz, M[1][m][3] * dw))), op + 1);
        __builtin_nontemporal_store(
            fmaf(M[2][m][0], dx, fmaf(M[2][m][1], dy, fmaf(M[2][m][2], dz, M[2][m][3] * dw))), op + 2);
    }
}

extern "C" void kernel_launch(void* const* d_in, const int* in_sizes, int n_in,
                              void* d_out, int out_size, void* d_ws, size_t ws_size,
                              hipStream_t stream) {
    // d_in[0] = light (3) -- unused by the reference computation
    const float* normals = (const float*)d_in[1];   // B*V*3
    const float* sh      = (const float*)d_in[2];   // 27
    float* out           = (float*)d_out;           // B*V*3

    const int grid = SH_B * (QTR / 256);            // 16 * 256 = 4096 blocks
    sh_lighting_kernel<<<grid, 256, 0, stream>>>(normals, sh, out);
}